// Round 5
// baseline (103.250 us; speedup 1.0000x reference)
//
#include <hip/hip_runtime.h>

#define NB 4
#define NC 32
#define NH 32
#define NW 32
#define KK 288                   // 32*3*3 patch length
#define PLANE (NB*NC*NH*NW)      // 131072 elements per plane
#define CHALF 16                 // channels per block (split reduction)

typedef float v2f __attribute__((ext_vector_type(2)));

__device__ __forceinline__ float s3(float v) { return sqrtf(sqrtf(sqrtf(v))); }
__device__ __forceinline__ v2f pkfma(v2f a, v2f b, v2f c) { return __builtin_elementwise_fma(a, b, c); }
__device__ __forceinline__ v2f pkmax(v2f a, v2f b) { return __builtin_elementwise_max(a, b); }

// Zero-mean weight rows; PAIR-INTERLEAVED packed layout for v_pk_* math:
// pair q = cog*8 + (co&7) covers (co0 = cog*16 + t, co1 = co0 + 8); slot = A/B.
// Per (q,c,r): 8 floats {A.k0,B.k0, A.k1,B.k1, A.k2,B.k2, pad,pad}.
// float offset = ((q*NC + c)*3 + r)*8 + kw*2 + slot.
__global__ __launch_bounds__(256) void prep_weights_k(
        const float* __restrict__ w1, const float* __restrict__ w2,
        float* __restrict__ wf1, float* __restrict__ wf2)
{
    const int row = blockIdx.x;                   // 0..63
    const float* src = (row < NC) ? w1 : w2;
    float* dst = (row < NC) ? wf1 : wf2;
    const int co = row & (NC - 1);
    const int tid = threadIdx.x;
    __shared__ float red[256];
    const float a = src[co*KK + tid];                              // tid < 256 < 288
    const float b = (tid + 256 < KK) ? src[co*KK + tid + 256] : 0.0f;
    red[tid] = a + b;
    __syncthreads();
    for (int s = 128; s > 0; s >>= 1) {
        if (tid < s) red[tid] += red[tid + s];
        __syncthreads();
    }
    const float mean = red[0] * (1.0f / (float)KK);
    const int q    = ((co >> 4) << 3) | (co & 7);
    const int slot = (co >> 3) & 1;
    {
        const int e = tid, c = e / 9, r9 = e - c*9, r = r9 / 3, kw = r9 - r*3;
        dst[((q*NC + c)*3 + r)*8 + kw*2 + slot] = a - mean;
    }
    if (tid + 256 < KK) {
        const int e = tid + 256, c = e / 9, r9 = e - c*9, r = r9 / 3, kw = r9 - r*3;
        dst[((q*NC + c)*3 + r)*8 + kw*2 + slot] = b - mean;
    }
}

// Half-channel norm-dist conv, packed over the co pair, WAVE-UNIFORM weights.
// Block = 512 threads (8 waves). Wave w handles co pair q = cog*8 + w for TWO
// output rows (2*h2, 2*h2+1): lane = rs*32 + px. Weight index is wave-uniform
// -> readfirstlane forces s_load (scalar pipe), freeing VMEM + VALU.
// Grid = (h2=16, cog*2+chalf=4, b=4) -> 256 blocks, 8 waves/CU, 2 waves/SIMD.
// STAGE1: stages x/l/u. STAGE2: stages s3(p0+p1) from conv1 partials.
// Both write partial (pre-root) sums to pY/pL/pU at [chalf*PLANE + o].
template<bool STAGE2>
__global__ __launch_bounds__(512, 1) void normdist_conv_k(
    const float* __restrict__ sy,     // stage1: x plane | stage2: conv1 Y partials [2][PLANE]
    const float* __restrict__ sl,
    const float* __restrict__ su,
    const float* __restrict__ wf,     // prepped pair-interleaved weights
    float* __restrict__ pY, float* __restrict__ pL, float* __restrict__ pU)
{
    const int h2    = blockIdx.x;          // output rows 2*h2, 2*h2+1
    const int cog   = blockIdx.y >> 1;
    const int chalf = blockIdx.y & 1;
    const int ch0   = chalf * CHALF;
    const int b     = blockIdx.z;
    const int tid   = threadIdx.x;
    const int lane  = tid & 63;
    const int wv    = tid >> 6;            // wave id 0..7
    const int px    = lane & 31;           // pixel column
    const int rs    = lane >> 5;           // row select 0/1

    // Patch halo, xlu-interleaved: [c<16][r<4][col<34] float4 (w unused). 34816 B.
    __shared__ float4 sP[CHALF*4*34];

    for (int i = tid; i < CHALF*4*34; i += 512) {
        const int c   = i / 136;
        const int rem = i - c*136;
        const int r   = rem / 34;
        const int col = rem - r*34;
        const int gh  = 2*h2 + r - 1;
        const int gw  = col - 1;
        float vx = 0.0f, vl = 0.0f, vu = 0.0f;
        if ((unsigned)gh < NH && (unsigned)gw < NW) {
            const int g = ((b*NC + ch0 + c)*NH + gh)*NW + gw;
            if (STAGE2) {   // combine conv1 halves + eighth-root (relu no-op: >=0)
                vx = s3(sy[g] + sy[PLANE + g]);
                vl = s3(sl[g] + sl[PLANE + g]);
                vu = s3(su[g] + su[PLANE + g]);
            } else {
                vx = sy[g]; vl = sl[g]; vu = su[g];
            }
        }
        sP[i] = make_float4(vx, vl, vu, 0.0f);
    }
    __syncthreads();

    // Wave-uniform weight base: q = cog*8 + wv, starting at channel ch0.
    const int q = cog*8 + wv;
    const int widx = __builtin_amdgcn_readfirstlane((q*NC + ch0)*6);
    const float4* wq = (const float4*)wf + widx;   // 6 float4 per channel

    v2f aY = {0.0f, 0.0f}, aL = {0.0f, 0.0f}, aU = {0.0f, 0.0f};

    // Packed tap: w = {wA, wB} for the co pair; p broadcast.
    auto tap2 = [&](v2f w, const float4& p) {
        const v2f px2 = {p.x, p.x};
        const v2f py2 = {p.y, p.y};
        const v2f pz2 = {p.z, p.z};
        const v2f d  = px2 - w;             // y: |d|^8 = ((d^2)^2)^2
        const v2f d2 = d*d, d4 = d2*d2;
        aY = pkfma(d4, d4, aY);
        const v2f a  = py2 - w;             // dl: max(a, nb, 0)^8
        const v2f nb = w - pz2;
        const v2f z  = {0.0f, 0.0f};
        const v2f m  = pkmax(pkmax(a, nb), z);
        const v2f m2 = m*m, m4 = m2*m2;
        aL = pkfma(m4, m4, aL);
        const v2f a2 = a*a, q2 = nb*nb;     // du: max(a^2, nb^2)^4
        const v2f mm2 = pkmax(a2, q2);
        const v2f mm4 = mm2*mm2;
        aU = pkfma(mm4, mm4, aU);
    };

    // Software-pipelined weight fetch (scalar loads): fetch c+1 while computing c.
    float4 c0 = wq[0], c1 = wq[1], c2 = wq[2], c3 = wq[3], c4 = wq[4], c5 = wq[5];

    for (int c = 0; c < CHALF; ++c) {
        const int cn = (c < CHALF-1) ? c + 1 : c;
        const float4 n0 = wq[cn*6+0], n1 = wq[cn*6+1], n2 = wq[cn*6+2];
        const float4 n3 = wq[cn*6+3], n4 = wq[cn*6+4], n5 = wq[cn*6+5];

        const int pb = c*136 + rs*34 + px;
        const float4 p00 = sP[pb +  0], p01 = sP[pb +  1], p02 = sP[pb +  2];
        const float4 p10 = sP[pb + 34], p11 = sP[pb + 35], p12 = sP[pb + 36];
        const float4 p20 = sP[pb + 68], p21 = sP[pb + 69], p22 = sP[pb + 70];

        tap2((v2f){c0.x, c0.y}, p00); tap2((v2f){c0.z, c0.w}, p01); tap2((v2f){c1.x, c1.y}, p02);
        tap2((v2f){c2.x, c2.y}, p10); tap2((v2f){c2.z, c2.w}, p11); tap2((v2f){c3.x, c3.y}, p12);
        tap2((v2f){c4.x, c4.y}, p20); tap2((v2f){c4.z, c4.w}, p21); tap2((v2f){c5.x, c5.y}, p22);

        c0 = n0; c1 = n1; c2 = n2; c3 = n3; c4 = n4; c5 = n5;
    }

    const int co0 = cog*16 + wv;
    const int h0  = 2*h2 + rs;
    const int o0 = ((b*NC + co0)*NH + h0)*NW + px;
    const int o1 = o0 + 8*NH*NW;
    pY[chalf*PLANE + o0] = aY.x;
    pL[chalf*PLANE + o0] = aL.x;
    pU[chalf*PLANE + o0] = aU.x;
    pY[chalf*PLANE + o1] = aY.y;
    pL[chalf*PLANE + o1] = aL.y;
    pU[chalf*PLANE + o1] = aU.y;
}

// Combine conv2 halves, eighth-root, add residual, relu, write out. float4-vectorized.
__global__ __launch_bounds__(256) void epilogue_k(
    const float* __restrict__ pY, const float* __restrict__ pL, const float* __restrict__ pU,
    const float* __restrict__ x,  const float* __restrict__ l,  const float* __restrict__ u,
    float* __restrict__ out)
{
    const int i = blockIdx.x*256 + threadIdx.x;     // float4 index, PLANE/4 total
    const float4* pY4 = (const float4*)pY;
    const float4* pL4 = (const float4*)pL;
    const float4* pU4 = (const float4*)pU;
    const float4* x4  = (const float4*)x;
    const float4* l4  = (const float4*)l;
    const float4* u4  = (const float4*)u;
    float4* out4 = (float4*)out;
    const int Q = PLANE/4;

    const float4 ya = pY4[i], yb = pY4[Q + i];
    const float4 la = pL4[i], lb = pL4[Q + i];
    const float4 ua = pU4[i], ub = pU4[Q + i];
    const float4 xr = x4[i], lr = l4[i], ur = u4[i];

    float4 oy, ol, ou;
    oy.x = fmaxf(s3(ya.x + yb.x) + xr.x, 0.0f);
    oy.y = fmaxf(s3(ya.y + yb.y) + xr.y, 0.0f);
    oy.z = fmaxf(s3(ya.z + yb.z) + xr.z, 0.0f);
    oy.w = fmaxf(s3(ya.w + yb.w) + xr.w, 0.0f);
    ol.x = fmaxf(s3(la.x + lb.x) + lr.x, 0.0f);
    ol.y = fmaxf(s3(la.y + lb.y) + lr.y, 0.0f);
    ol.z = fmaxf(s3(la.z + lb.z) + lr.z, 0.0f);
    ol.w = fmaxf(s3(la.w + lb.w) + lr.w, 0.0f);
    ou.x = fmaxf(s3(ua.x + ub.x) + ur.x, 0.0f);
    ou.y = fmaxf(s3(ua.y + ub.y) + ur.y, 0.0f);
    ou.z = fmaxf(s3(ua.z + ub.z) + ur.z, 0.0f);
    ou.w = fmaxf(s3(ua.w + ub.w) + ur.w, 0.0f);

    out4[i]       = oy;
    out4[Q + i]   = ol;
    out4[2*Q + i] = ou;
}

extern "C" void kernel_launch(void* const* d_in, const int* in_sizes, int n_in,
                              void* d_out, int out_size, void* d_ws, size_t ws_size,
                              hipStream_t stream)
{
    const float* x  = (const float*)d_in[0];
    const float* l  = (const float*)d_in[1];
    const float* u  = (const float*)d_in[2];
    const float* w1 = (const float*)d_in[3];
    const float* w2 = (const float*)d_in[4];
    float* ws  = (float*)d_ws;
    float* wf1 = ws;                        // 12288 floats (pair-interleaved layout)
    float* wf2 = wf1 + 12288;
    float* p1Y = wf2 + 12288;               // conv1 partials: [2][PLANE] each
    float* p1L = p1Y + 2*PLANE;
    float* p1U = p1L + 2*PLANE;
    float* p2Y = p1U + 2*PLANE;             // conv2 partials
    float* p2L = p2Y + 2*PLANE;
    float* p2U = p2L + 2*PLANE;
    float* out = (float*)d_out;

    prep_weights_k<<<64, 256, 0, stream>>>(w1, w2, wf1, wf2);

    dim3 grd(NH/2, 4, NB);                  // h2, cog*2+chalf, b  -> 256 blocks
    normdist_conv_k<false><<<grd, 512, 0, stream>>>(x, l, u, wf1, p1Y, p1L, p1U);
    normdist_conv_k<true ><<<grd, 512, 0, stream>>>(p1Y, p1L, p1U, wf2, p2Y, p2L, p2U);
    epilogue_k<<<PLANE/1024, 256, 0, stream>>>(p2Y, p2L, p2U, x, l, u, out);
}